// Round 2
// baseline (2277.184 us; speedup 1.0000x reference)
//
#include <hip/hip_runtime.h>
#include <hip/hip_bf16.h>

typedef __bf16 bf16_t;
typedef __bf16 bf16x4 __attribute__((ext_vector_type(4)));
typedef __bf16 bf16x8 __attribute__((ext_vector_type(8)));
typedef float f32x4 __attribute__((ext_vector_type(4)));

constexpr int T_STEPS = 50;
constexpr int B_SZ = 1024;
constexpr int NP_SZ = 512;
constexpr int NH_SZ = 512;
constexpr int NG_SZ = 4096;

// async 16B/lane global->LDS. LDS dest is wave-uniform base; HW deposits lane i at base + i*16.
__device__ __forceinline__ void async16(const bf16_t* g, bf16_t* l) {
    __builtin_amdgcn_global_load_lds((const __attribute__((address_space(1))) void*)g,
                                     (__attribute__((address_space(3))) void*)l, 16, 0, 0);
}

// ---------------- fp32 -> bf16 convert ----------------
__global__ __launch_bounds__(256) void cvt_f32_bf16(const float* __restrict__ src,
                                                    bf16_t* __restrict__ dst, int n4) {
    int i = blockIdx.x * blockDim.x + threadIdx.x;
    if (i >= n4) return;
    float4 v = ((const float4*)src)[i];
    bf16x4 o;
    o[0] = (bf16_t)v.x; o[1] = (bf16_t)v.y; o[2] = (bf16_t)v.z; o[3] = (bf16_t)v.w;
    ((bf16x4*)dst)[i] = o;
}

// ---------------- 2-phase pipelined GEMM: C = ep(A[M,K] @ B[N,K]^T) ----------------
// LDS layout: fragment order. Chunk c = (row-subtile s, k-chunk kk), c = s*KC + kk.
// Each chunk = 16 rows x 32 cols = 64 lanes x 16B contiguous; lane l holds rows
// (s*16 + (l&15)), cols kk*32 + (l>>4)*8 .. +8 == exactly its MFMA fragment.
// Double-buffered: prefetch tile t+1 issued BEFORE compute of tile t; single barrier/iter.
// BK = K-depth per iteration (32 or 64): BK=64 halves the serial latency chain.
// SWZ: bijective XCD chunk swizzle (requires nwg % 8 == 0).
// EP: 0 = +bias f32 out | 1 = +bias bf16 out | 2 = relu bf16 out
template <int BM, int BN, int BK, int EP, bool SWZ>
__global__ __launch_bounds__(256) void gemm16(const bf16_t* __restrict__ A,
                                              const bf16_t* __restrict__ Bm,
                                              const float* __restrict__ bias,
                                              void* __restrict__ Cout, int M, int N, int K) {
    constexpr int ASUB = BM / 16, BSUB = BN / 16, NSUB = ASUB + BSUB;
    constexpr int KC = BK / 32;        // k-chunks per iter
    constexpr int NCH = NSUB * KC;     // LDS chunks per buffer
    static_assert(NCH % 4 == 0, "chunk split over 4 waves");
    constexpr int PER_WAVE = NCH / 4;
    constexpr int MT = BM / 32, NT = BN / 32;
    constexpr int BUF = NCH * 512;
    __shared__ bf16_t lds[2 * BUF];

    const int tid = threadIdx.x, lane = tid & 63, wave = tid >> 6;
    const int wm = wave >> 1, wn = wave & 1;
    const int l15 = lane & 15, quad = lane >> 4;

    int bx = blockIdx.x, by = blockIdx.y;
    if constexpr (SWZ) {
        const int nwg = gridDim.x * gridDim.y;  // launcher guarantees nwg % 8 == 0
        int id = by * gridDim.x + bx;
        id = (id & 7) * (nwg >> 3) + (id >> 3);  // contiguous chunk per XCD
        bx = id % gridDim.x;
        by = id / gridDim.x;
    }
    const int bm0 = by * BM, bn0 = bx * BN;

    // per-lane staging source pointers (advance by BK elems per K-iter)
    const bf16_t* gsrc[PER_WAVE];
    bf16_t* ldst[PER_WAVE];
#pragma unroll
    for (int q = 0; q < PER_WAVE; q++) {
        int c = wave * PER_WAVE + q;
        int s = c / KC, kk = c % KC;
        if (s < ASUB)
            gsrc[q] = A + (size_t)(bm0 + s * 16 + l15) * K + kk * 32 + quad * 8;
        else
            gsrc[q] = Bm + (size_t)(bn0 + (s - ASUB) * 16 + l15) * K + kk * 32 + quad * 8;
        ldst[q] = &lds[c * 512];
    }

    f32x4 acc[MT][NT];
#pragma unroll
    for (int i = 0; i < MT; i++)
#pragma unroll
        for (int j = 0; j < NT; j++) acc[i][j] = f32x4{0.f, 0.f, 0.f, 0.f};

    const int nk = K / BK;
    // prologue: stage tile 0 into buffer 0
#pragma unroll
    for (int q = 0; q < PER_WAVE; q++) async16(gsrc[q], ldst[q]);
    __syncthreads();

    for (int t = 0; t < nk; t++) {
        const int cur = (t & 1) * BUF, nxt = BUF - cur;
        if (t + 1 < nk) {
#pragma unroll
            for (int q = 0; q < PER_WAVE; q++) async16(gsrc[q] + (t + 1) * BK, ldst[q] + nxt);
        }
#pragma unroll
        for (int kk = 0; kk < KC; kk++) {
            bf16x8 af[MT], bfg[NT];
#pragma unroll
            for (int i = 0; i < MT; i++)
                af[i] = *(const bf16x8*)&lds[cur + ((wm * MT + i) * KC + kk) * 512 + lane * 8];
#pragma unroll
            for (int j = 0; j < NT; j++)
                bfg[j] = *(const bf16x8*)&lds[cur + ((ASUB + wn * NT + j) * KC + kk) * 512 + lane * 8];
#pragma unroll
            for (int i = 0; i < MT; i++)
#pragma unroll
                for (int j = 0; j < NT; j++)
                    acc[i][j] = __builtin_amdgcn_mfma_f32_16x16x32_bf16(af[i], bfg[j], acc[i][j], 0, 0, 0);
        }
        __syncthreads();  // drains prefetch vmcnt + protects cur for overwrite at t+2
    }

// epilogue: C/D layout col=lane&15, row=quad*4+reg
#pragma unroll
    for (int j = 0; j < NT; j++) {
        const int col = bn0 + wn * (BN / 2) + j * 16 + l15;
        float bb = (EP == 2) ? 0.f : bias[col];
#pragma unroll
        for (int i = 0; i < MT; i++) {
#pragma unroll
            for (int r = 0; r < 4; r++) {
                const int row = bm0 + wm * (BM / 2) + i * 16 + quad * 4 + r;
                float x = acc[i][j][r];
                if constexpr (EP == 0) {
                    ((float*)Cout)[(size_t)row * N + col] = x + bb;
                } else if constexpr (EP == 1) {
                    ((bf16_t*)Cout)[(size_t)row * N + col] = (bf16_t)(x + bb);
                } else {
                    ((bf16_t*)Cout)[(size_t)row * N + col] = (bf16_t)fmaxf(x, 0.f);
                }
            }
        }
    }
}

// ---------------- fused gates GEMM + LSTM cell ----------------
// Block computes a 32(row b) x 32(col n) tile of hx/cx; accumulates all 4 gate slices
// of w_hh for those n. Grid (16,32) = 512 blocks -> 2 blocks/CU for TLP.
// BK=64 double-buffered pipeline: 8 serial iters instead of 16.
__global__ __launch_bounds__(256) void gates_cell(
    const bf16_t* __restrict__ hx_in, const bf16_t* __restrict__ whh,
    const float* __restrict__ vt, const float* __restrict__ wih,
    const float* __restrict__ bih, const float* __restrict__ bhh,
    float* __restrict__ cx, bf16_t* __restrict__ hx_out) {
    // row-subtiles: 0..1 = A (32 rows of hx), 2..9 = B (4 gates x 2 halves of 32 n-cols)
    // chunk c = s*2 + kk (kk = k-chunk within BK=64)
    constexpr int NCH = 20, BUF = NCH * 512, PW = 5;
    __shared__ bf16_t lds[2 * BUF];
    const int tid = threadIdx.x, lane = tid & 63, wave = tid >> 6;
    const int wm = wave >> 1, wn = wave & 1;
    const int l15 = lane & 15, quad = lane >> 4;
    const int bm0 = blockIdx.y * 32, bn0 = blockIdx.x * 32;

    const bf16_t* gsrc[PW];
    bf16_t* ldst[PW];
#pragma unroll
    for (int q = 0; q < PW; q++) {
        int c = wave * PW + q;
        int s = c >> 1, kk = c & 1;
        if (s < 2) {
            gsrc[q] = hx_in + (size_t)(bm0 + s * 16 + l15) * NH_SZ + kk * 32 + quad * 8;
        } else {
            int sb = s - 2, gi = sb >> 1, h = sb & 1;
            gsrc[q] = whh + (size_t)(gi * NH_SZ + bn0 + h * 16 + l15) * NH_SZ + kk * 32 + quad * 8;
        }
        ldst[q] = &lds[c * 512];
    }

    f32x4 acc[4];
#pragma unroll
    for (int g = 0; g < 4; g++) acc[g] = f32x4{0.f, 0.f, 0.f, 0.f};

    constexpr int NK = NH_SZ / 64;
#pragma unroll
    for (int q = 0; q < PW; q++) async16(gsrc[q], ldst[q]);
    __syncthreads();

    for (int t = 0; t < NK; t++) {
        const int cur = (t & 1) * BUF, nxt = BUF - cur;
        if (t + 1 < NK) {
#pragma unroll
            for (int q = 0; q < PW; q++) async16(gsrc[q] + (t + 1) * 64, ldst[q] + nxt);
        }
#pragma unroll
        for (int kk = 0; kk < 2; kk++) {
            bf16x8 af = *(const bf16x8*)&lds[cur + (wm * 2 + kk) * 512 + lane * 8];
            bf16x8 bg[4];
#pragma unroll
            for (int g = 0; g < 4; g++)
                bg[g] = *(const bf16x8*)&lds[cur + ((2 + g * 2 + wn) * 2 + kk) * 512 + lane * 8];
#pragma unroll
            for (int g = 0; g < 4; g++)
                acc[g] = __builtin_amdgcn_mfma_f32_16x16x32_bf16(af, bg[g], acc[g], 0, 0, 0);
        }
        __syncthreads();
    }

    const int col = bn0 + wn * 16 + l15;
    float bi[4], w0[4], w1[4];
#pragma unroll
    for (int g = 0; g < 4; g++) {
        int gc = g * NH_SZ + col;
        bi[g] = bih[gc] + bhh[gc];
        w0[g] = wih[gc * 2];
        w1[g] = wih[gc * 2 + 1];
    }
    const int row0 = bm0 + wm * 16 + quad * 4;
#pragma unroll
    for (int r = 0; r < 4; r++) {
        const int row = row0 + r;
        float v0 = vt[row * 2], v1 = vt[row * 2 + 1];
        float xi = acc[0][r] + bi[0] + v0 * w0[0] + v1 * w1[0];
        float xf = acc[1][r] + bi[1] + v0 * w0[1] + v1 * w1[1];
        float xg = acc[2][r] + bi[2] + v0 * w0[2] + v1 * w1[2];
        float xo = acc[3][r] + bi[3] + v0 * w0[3] + v1 * w1[3];
        float ig = 1.f / (1.f + __expf(-xi));
        float fg = 1.f / (1.f + __expf(-xf));
        float gg = tanhf(xg);
        float og = 1.f / (1.f + __expf(-xo));
        int idx = (row << 9) + col;
        float c = fg * cx[idx] + ig * gg;
        cx[idx] = c;
        hx_out[idx] = (bf16_t)(og * tanhf(c));
    }
}

// ---------------- host launcher ----------------
extern "C" void kernel_launch(void* const* d_in, const int* in_sizes, int n_in,
                              void* d_out, int out_size, void* d_ws, size_t ws_size,
                              hipStream_t stream) {
    const float* v    = (const float*)d_in[0];
    const float* p0   = (const float*)d_in[1];
    const float* e1w  = (const float*)d_in[2];
    const float* e1b  = (const float*)d_in[3];
    const float* e2w  = (const float*)d_in[4];
    const float* e2b  = (const float*)d_in[5];
    const float* wih  = (const float*)d_in[6];
    const float* whh  = (const float*)d_in[7];
    const float* bih  = (const float*)d_in[8];
    const float* bhh  = (const float*)d_in[9];
    const float* gw   = (const float*)d_in[10];
    const float* decw = (const float*)d_in[11];
    const float* decb = (const float*)d_in[12];
    float* out = (float*)d_out;

    size_t off = 0;
    auto take = [&](size_t bytes) {
        size_t o = off;
        off += (bytes + 255) & ~(size_t)255;
        return (void*)((char*)d_ws + o);
    };
    bf16_t* p0b   = (bf16_t*)take((size_t)B_SZ * NP_SZ * 2);
    bf16_t* e1wb  = (bf16_t*)take((size_t)NH_SZ * NP_SZ * 2);
    bf16_t* e2wb  = (bf16_t*)take((size_t)NH_SZ * NP_SZ * 2);
    bf16_t* whhb  = (bf16_t*)take((size_t)4 * NH_SZ * NH_SZ * 2);
    bf16_t* gwb   = (bf16_t*)take((size_t)NG_SZ * NH_SZ * 2);
    bf16_t* decwb = (bf16_t*)take((size_t)NP_SZ * NG_SZ * 2);
    bf16_t* hxA   = (bf16_t*)take((size_t)B_SZ * NH_SZ * 2);
    bf16_t* hxB   = (bf16_t*)take((size_t)B_SZ * NH_SZ * 2);
    float*  cxf   = (float*)take((size_t)B_SZ * NH_SZ * 4);

    // decoder chunk size: largest divisor of T that fits remaining workspace
    const size_t per_step = (size_t)B_SZ * NG_SZ * 2;  // 8 MB bf16
    int C = 1;
    for (int c : {25, 10, 5, 2, 1}) {
        if (off + (size_t)c * per_step <= ws_size) { C = c; break; }
    }
    bf16_t* gbuf = (bf16_t*)take((size_t)C * per_step);

    auto cvt = [&](const float* s, bf16_t* d, int n) {
        int n4 = n >> 2;
        cvt_f32_bf16<<<dim3((n4 + 255) / 256), dim3(256), 0, stream>>>(s, d, n4);
    };
    cvt(p0, p0b, B_SZ * NP_SZ);
    cvt(e1w, e1wb, NH_SZ * NP_SZ);
    cvt(e2w, e2wb, NH_SZ * NP_SZ);
    cvt(whh, whhb, 4 * NH_SZ * NH_SZ);
    cvt(gw, gwb, NG_SZ * NH_SZ);
    cvt(decw, decwb, NP_SZ * NG_SZ);

    // encoders: hx0 (bf16), cx0 (f32). 64x64 tiles -> 128 blocks each.
    gemm16<64, 64, 32, 1, false><<<dim3(NH_SZ / 64, B_SZ / 64), 256, 0, stream>>>(
        p0b, e1wb, e1b, hxA, B_SZ, NH_SZ, NP_SZ);
    gemm16<64, 64, 32, 0, false><<<dim3(NH_SZ / 64, B_SZ / 64), 256, 0, stream>>>(
        p0b, e2wb, e2b, cxf, B_SZ, NH_SZ, NP_SZ);

    bf16_t* hin = hxA;
    bf16_t* hout = hxB;
    for (int t = 0; t < T_STEPS; t++) {
        const float* vt = v + (size_t)t * B_SZ * 2;
        // fused gates + cell: grid (NH/32, B/32) = (16,32) = 512 blocks (2/CU), BK=64
        gates_cell<<<dim3(NH_SZ / 32, B_SZ / 32), 256, 0, stream>>>(
            hin, whhb, vt, wih, bih, bhh, cxf, hout);
        // g = relu(hx @ g_w^T): 64x64 tiles, BK=64 -> (64,16) = 1024 blocks (4/CU)
        gemm16<64, 64, 64, 2, false><<<dim3(NG_SZ / 64, B_SZ / 64), 256, 0, stream>>>(
            hout, gwb, nullptr, gbuf + (size_t)(t % C) * B_SZ * NG_SZ, B_SZ, NG_SZ, NH_SZ);
        // chunked batched decoder: 128x128 tiles (800 blocks = 3.1/CU) + XCD chunk swizzle
        if ((t + 1) % C == 0) {
            int t0 = t + 1 - C;
            gemm16<128, 128, 32, 0, true><<<dim3(NP_SZ / 128, (C * B_SZ) / 128), 256, 0, stream>>>(
                gbuf, decwb, decb, out + (size_t)t0 * B_SZ * NP_SZ, C * B_SZ, NP_SZ, NG_SZ);
        }
        // swap hx buffers
        bf16_t* tmp = hin; hin = hout; hout = tmp;
    }
}

// Round 4
// 1819.213 us; speedup vs baseline: 1.2517x; 1.2517x over previous
//
#include <hip/hip_runtime.h>
#include <hip/hip_bf16.h>

typedef __bf16 bf16_t;
typedef __bf16 bf16x4 __attribute__((ext_vector_type(4)));
typedef __bf16 bf16x8 __attribute__((ext_vector_type(8)));
typedef float f32x4 __attribute__((ext_vector_type(4)));

constexpr int T_STEPS = 50;
constexpr int B_SZ = 1024;
constexpr int NP_SZ = 512;
constexpr int NH_SZ = 512;
constexpr int NG_SZ = 4096;

// async 16B/lane global->LDS. LDS dest is wave-uniform base; HW deposits lane i at base + i*16.
__device__ __forceinline__ void async16(const bf16_t* g, bf16_t* l) {
    __builtin_amdgcn_global_load_lds((const __attribute__((address_space(1))) void*)g,
                                     (__attribute__((address_space(3))) void*)l, 16, 0, 0);
}

// counted vmcnt wait (immediate must be a literal -> constexpr dispatch)
template <int N> __device__ __forceinline__ void vmwait() {
    if constexpr (N == 0) asm volatile("s_waitcnt vmcnt(0)" ::: "memory");
    else if constexpr (N == 2) asm volatile("s_waitcnt vmcnt(2)" ::: "memory");
    else if constexpr (N == 3) asm volatile("s_waitcnt vmcnt(3)" ::: "memory");
    else if constexpr (N == 4) asm volatile("s_waitcnt vmcnt(4)" ::: "memory");
    else static_assert(N < 0, "add vmcnt literal");
}

// ---------------- fp32 -> bf16 convert ----------------
__global__ __launch_bounds__(256) void cvt_f32_bf16(const float* __restrict__ src,
                                                    bf16_t* __restrict__ dst, int n4) {
    int i = blockIdx.x * blockDim.x + threadIdx.x;
    if (i >= n4) return;
    float4 v = ((const float4*)src)[i];
    bf16x4 o;
    o[0] = (bf16_t)v.x; o[1] = (bf16_t)v.y; o[2] = (bf16_t)v.z; o[3] = (bf16_t)v.w;
    ((bf16x4*)dst)[i] = o;
}

// ---------------- counted-vmcnt depth-2 GEMM: C = ep(A[M,K] @ B[N,K]^T) ----------------
// LDS fragment order: chunk = 16 rows x 32 cols = 64 lanes x 16B; lane l holds rows
// (s*16+(l&15)), cols (l>>4)*8.. == its MFMA fragment. Triple-buffered, 2 tiles in
// flight; per-iter: s_waitcnt vmcnt(PW) (tile t landed, t+1 still flying) -> s_barrier
// -> issue tile t+2 -> ds_read+MFMA tile t. vmcnt never drains to 0 in the loop (T4).
// SWZ: bijective XCD chunk swizzle (requires nwg % 8 == 0).
// EP: 0 = +bias f32 out | 1 = +bias bf16 out | 2 = relu bf16 out
template <int BM, int BN, int EP, bool SWZ>
__global__ __launch_bounds__(256) void gemm16(const bf16_t* __restrict__ A,
                                              const bf16_t* __restrict__ Bm,
                                              const float* __restrict__ bias,
                                              void* __restrict__ Cout, int M, int N, int K) {
    constexpr int ASUB = BM / 16, BSUB = BN / 16, NSUB = ASUB + BSUB;
    static_assert(NSUB % 4 == 0, "subtile split over 4 waves");
    constexpr int PW = NSUB / 4;  // staged chunks per wave per tile
    constexpr int MT = BM / 32, NT = BN / 32;
    constexpr int BUF = NSUB * 512;
    __shared__ bf16_t lds[3 * BUF];

    const int tid = threadIdx.x, lane = tid & 63, wave = tid >> 6;
    const int wm = wave >> 1, wn = wave & 1;
    const int l15 = lane & 15, quad = lane >> 4;

    int bx = blockIdx.x, by = blockIdx.y;
    if constexpr (SWZ) {
        const int nwg = gridDim.x * gridDim.y;  // launcher guarantees nwg % 8 == 0
        int id = by * gridDim.x + bx;
        id = (id & 7) * (nwg >> 3) + (id >> 3);  // contiguous chunk per XCD
        bx = id % gridDim.x;
        by = id / gridDim.x;
    }
    const int bm0 = by * BM, bn0 = bx * BN;

    // per-lane staging source pointers (advance by 32 elems per K-iter)
    const bf16_t* gsrc[PW];
    bf16_t* ldst[PW];
#pragma unroll
    for (int q = 0; q < PW; q++) {
        int s = wave * PW + q;
        if (s < ASUB)
            gsrc[q] = A + (size_t)(bm0 + s * 16 + l15) * K + quad * 8;
        else
            gsrc[q] = Bm + (size_t)(bn0 + (s - ASUB) * 16 + l15) * K + quad * 8;
        ldst[q] = &lds[s * 512];
    }

    f32x4 acc[MT][NT];
#pragma unroll
    for (int i = 0; i < MT; i++)
#pragma unroll
        for (int j = 0; j < NT; j++) acc[i][j] = f32x4{0.f, 0.f, 0.f, 0.f};

    const int nk = K / 32;  // nk >= 2 for all our shapes
    // prologue: tiles 0,1 into buffers 0,1
#pragma unroll
    for (int q = 0; q < PW; q++) async16(gsrc[q], ldst[q]);
#pragma unroll
    for (int q = 0; q < PW; q++) async16(gsrc[q] + 32, ldst[q] + BUF);

    int c0 = 0, c1 = BUF, c2 = 2 * BUF;
    for (int t = 0; t < nk - 1; t++) {
        vmwait<PW>();                      // tile t landed; tile t+1 may still fly
        __builtin_amdgcn_s_barrier();      // all waves agree tile t is in LDS
        if (t + 2 < nk) {
#pragma unroll
            for (int q = 0; q < PW; q++) async16(gsrc[q] + (t + 2) * 32, ldst[q] + c2);
        }
        bf16x8 af[MT], bfg[NT];
#pragma unroll
        for (int i = 0; i < MT; i++)
            af[i] = *(const bf16x8*)&lds[c0 + (wm * MT + i) * 512 + lane * 8];
#pragma unroll
        for (int j = 0; j < NT; j++)
            bfg[j] = *(const bf16x8*)&lds[c0 + (ASUB + wn * NT + j) * 512 + lane * 8];
#pragma unroll
        for (int i = 0; i < MT; i++)
#pragma unroll
            for (int j = 0; j < NT; j++)
                acc[i][j] = __builtin_amdgcn_mfma_f32_16x16x32_bf16(af[i], bfg[j], acc[i][j], 0, 0, 0);
        int tmp = c0; c0 = c1; c1 = c2; c2 = tmp;
    }
    // final tile: full drain
    vmwait<0>();
    __builtin_amdgcn_s_barrier();
    {
        bf16x8 af[MT], bfg[NT];
#pragma unroll
        for (int i = 0; i < MT; i++)
            af[i] = *(const bf16x8*)&lds[c0 + (wm * MT + i) * 512 + lane * 8];
#pragma unroll
        for (int j = 0; j < NT; j++)
            bfg[j] = *(const bf16x8*)&lds[c0 + (ASUB + wn * NT + j) * 512 + lane * 8];
#pragma unroll
        for (int i = 0; i < MT; i++)
#pragma unroll
            for (int j = 0; j < NT; j++)
                acc[i][j] = __builtin_amdgcn_mfma_f32_16x16x32_bf16(af[i], bfg[j], acc[i][j], 0, 0, 0);
    }

// epilogue: C/D layout col=lane&15, row=quad*4+reg
#pragma unroll
    for (int j = 0; j < NT; j++) {
        const int col = bn0 + wn * (BN / 2) + j * 16 + l15;
        float bb = (EP == 2) ? 0.f : bias[col];
#pragma unroll
        for (int i = 0; i < MT; i++) {
#pragma unroll
            for (int r = 0; r < 4; r++) {
                const int row = bm0 + wm * (BM / 2) + i * 16 + quad * 4 + r;
                float x = acc[i][j][r];
                if constexpr (EP == 0) {
                    ((float*)Cout)[(size_t)row * N + col] = x + bb;
                } else if constexpr (EP == 1) {
                    ((bf16_t*)Cout)[(size_t)row * N + col] = (bf16_t)(x + bb);
                } else {
                    ((bf16_t*)Cout)[(size_t)row * N + col] = (bf16_t)fmaxf(x, 0.f);
                }
            }
        }
    }
}

// ---------------- fused gates GEMM + LSTM cell ----------------
// Block computes a 64(row b) x 32(col n) tile of hx/cx; accumulates all 4 gate slices
// of w_hh. Grid (16,16) = 256 blocks. Same counted-vmcnt depth-2 pipeline (PW=3).
__global__ __launch_bounds__(256) void gates_cell(
    const bf16_t* __restrict__ hx_in, const bf16_t* __restrict__ whh,
    const float* __restrict__ vt, const float* __restrict__ wih,
    const float* __restrict__ bih, const float* __restrict__ bhh,
    float* __restrict__ cx, bf16_t* __restrict__ hx_out) {
    // chunks: 0..3 = A (64 rows of hx), 4..11 = B (4 gates x 2 halves of 32 n-cols)
    constexpr int NCH = 12, BUF = NCH * 512, PW = 3;
    __shared__ bf16_t lds[3 * BUF];
    const int tid = threadIdx.x, lane = tid & 63, wave = tid >> 6;
    const int wm = wave >> 1, wn = wave & 1;
    const int l15 = lane & 15, quad = lane >> 4;
    const int bm0 = blockIdx.y * 64, bn0 = blockIdx.x * 32;

    const bf16_t* gsrc[PW];
    bf16_t* ldst[PW];
#pragma unroll
    for (int q = 0; q < PW; q++) {
        int s = wave * PW + q;
        if (s < 4) {
            gsrc[q] = hx_in + (size_t)(bm0 + s * 16 + l15) * NH_SZ + quad * 8;
        } else {
            int sb = s - 4, gi = sb >> 1, h = sb & 1;
            gsrc[q] = whh + (size_t)(gi * NH_SZ + bn0 + h * 16 + l15) * NH_SZ + quad * 8;
        }
        ldst[q] = &lds[s * 512];
    }

    f32x4 acc[4][2];
#pragma unroll
    for (int g = 0; g < 4; g++)
#pragma unroll
        for (int i = 0; i < 2; i++) acc[g][i] = f32x4{0.f, 0.f, 0.f, 0.f};

    constexpr int NK = NH_SZ / 32;  // 16
#pragma unroll
    for (int q = 0; q < PW; q++) async16(gsrc[q], ldst[q]);
#pragma unroll
    for (int q = 0; q < PW; q++) async16(gsrc[q] + 32, ldst[q] + BUF);

    int c0 = 0, c1 = BUF, c2 = 2 * BUF;
    for (int t = 0; t < NK - 1; t++) {
        vmwait<PW>();
        __builtin_amdgcn_s_barrier();
        if (t + 2 < NK) {
#pragma unroll
            for (int q = 0; q < PW; q++) async16(gsrc[q] + (t + 2) * 32, ldst[q] + c2);
        }
        bf16x8 af[2], bg[4];
#pragma unroll
        for (int i = 0; i < 2; i++)
            af[i] = *(const bf16x8*)&lds[c0 + (wm * 2 + i) * 512 + lane * 8];
#pragma unroll
        for (int g = 0; g < 4; g++)
            bg[g] = *(const bf16x8*)&lds[c0 + (4 + g * 2 + wn) * 512 + lane * 8];
#pragma unroll
        for (int g = 0; g < 4; g++)
#pragma unroll
            for (int i = 0; i < 2; i++)
                acc[g][i] = __builtin_amdgcn_mfma_f32_16x16x32_bf16(af[i], bg[g], acc[g][i], 0, 0, 0);
        int tmp = c0; c0 = c1; c1 = c2; c2 = tmp;
    }
    vmwait<0>();
    __builtin_amdgcn_s_barrier();
    {
        bf16x8 af[2], bg[4];
#pragma unroll
        for (int i = 0; i < 2; i++)
            af[i] = *(const bf16x8*)&lds[c0 + (wm * 2 + i) * 512 + lane * 8];
#pragma unroll
        for (int g = 0; g < 4; g++)
            bg[g] = *(const bf16x8*)&lds[c0 + (4 + g * 2 + wn) * 512 + lane * 8];
#pragma unroll
        for (int g = 0; g < 4; g++)
#pragma unroll
            for (int i = 0; i < 2; i++)
                acc[g][i] = __builtin_amdgcn_mfma_f32_16x16x32_bf16(af[i], bg[g], acc[g][i], 0, 0, 0);
    }

    const int col = bn0 + wn * 16 + l15;
    float bi[4], w0[4], w1[4];
#pragma unroll
    for (int g = 0; g < 4; g++) {
        int gc = g * NH_SZ + col;
        bi[g] = bih[gc] + bhh[gc];
        w0[g] = wih[gc * 2];
        w1[g] = wih[gc * 2 + 1];
    }
#pragma unroll
    for (int i = 0; i < 2; i++) {
#pragma unroll
        for (int r = 0; r < 4; r++) {
            const int row = bm0 + wm * 32 + i * 16 + quad * 4 + r;
            float v0 = vt[row * 2], v1 = vt[row * 2 + 1];
            float xi = acc[0][i][r] + bi[0] + v0 * w0[0] + v1 * w1[0];
            float xf = acc[1][i][r] + bi[1] + v0 * w0[1] + v1 * w1[1];
            float xg = acc[2][i][r] + bi[2] + v0 * w0[2] + v1 * w1[2];
            float xo = acc[3][i][r] + bi[3] + v0 * w0[3] + v1 * w1[3];
            float ig = 1.f / (1.f + __expf(-xi));
            float fg = 1.f / (1.f + __expf(-xf));
            float gg = tanhf(xg);
            float og = 1.f / (1.f + __expf(-xo));
            int idx = (row << 9) + col;
            float c = fg * cx[idx] + ig * gg;
            cx[idx] = c;
            hx_out[idx] = (bf16_t)(og * tanhf(c));
        }
    }
}

// ---------------- host launcher ----------------
extern "C" void kernel_launch(void* const* d_in, const int* in_sizes, int n_in,
                              void* d_out, int out_size, void* d_ws, size_t ws_size,
                              hipStream_t stream) {
    const float* v    = (const float*)d_in[0];
    const float* p0   = (const float*)d_in[1];
    const float* e1w  = (const float*)d_in[2];
    const float* e1b  = (const float*)d_in[3];
    const float* e2w  = (const float*)d_in[4];
    const float* e2b  = (const float*)d_in[5];
    const float* wih  = (const float*)d_in[6];
    const float* whh  = (const float*)d_in[7];
    const float* bih  = (const float*)d_in[8];
    const float* bhh  = (const float*)d_in[9];
    const float* gw   = (const float*)d_in[10];
    const float* decw = (const float*)d_in[11];
    const float* decb = (const float*)d_in[12];
    float* out = (float*)d_out;

    size_t off = 0;
    auto take = [&](size_t bytes) {
        size_t o = off;
        off += (bytes + 255) & ~(size_t)255;
        return (void*)((char*)d_ws + o);
    };
    bf16_t* p0b   = (bf16_t*)take((size_t)B_SZ * NP_SZ * 2);
    bf16_t* e1wb  = (bf16_t*)take((size_t)NH_SZ * NP_SZ * 2);
    bf16_t* e2wb  = (bf16_t*)take((size_t)NH_SZ * NP_SZ * 2);
    bf16_t* whhb  = (bf16_t*)take((size_t)4 * NH_SZ * NH_SZ * 2);
    bf16_t* gwb   = (bf16_t*)take((size_t)NG_SZ * NH_SZ * 2);
    bf16_t* decwb = (bf16_t*)take((size_t)NP_SZ * NG_SZ * 2);
    bf16_t* hxA   = (bf16_t*)take((size_t)B_SZ * NH_SZ * 2);
    bf16_t* hxB   = (bf16_t*)take((size_t)B_SZ * NH_SZ * 2);
    float*  cxf   = (float*)take((size_t)B_SZ * NH_SZ * 4);

    // decoder chunk size: largest divisor of T that fits remaining workspace
    const size_t per_step = (size_t)B_SZ * NG_SZ * 2;  // 8 MB bf16
    int C = 1;
    for (int c : {25, 10, 5, 2, 1}) {
        if (off + (size_t)c * per_step <= ws_size) { C = c; break; }
    }
    bf16_t* gbuf = (bf16_t*)take((size_t)C * per_step);

    auto cvt = [&](const float* s, bf16_t* d, int n) {
        int n4 = n >> 2;
        cvt_f32_bf16<<<dim3((n4 + 255) / 256), dim3(256), 0, stream>>>(s, d, n4);
    };
    cvt(p0, p0b, B_SZ * NP_SZ);
    cvt(e1w, e1wb, NH_SZ * NP_SZ);
    cvt(e2w, e2wb, NH_SZ * NP_SZ);
    cvt(whh, whhb, 4 * NH_SZ * NH_SZ);
    cvt(gw, gwb, NG_SZ * NH_SZ);
    cvt(decw, decwb, NP_SZ * NG_SZ);

    // encoders: hx0 (bf16), cx0 (f32). 64x64 tiles -> 128 blocks each.
    gemm16<64, 64, 1, false><<<dim3(NH_SZ / 64, B_SZ / 64), 256, 0, stream>>>(
        p0b, e1wb, e1b, hxA, B_SZ, NH_SZ, NP_SZ);
    gemm16<64, 64, 0, false><<<dim3(NH_SZ / 64, B_SZ / 64), 256, 0, stream>>>(
        p0b, e2wb, e2b, cxf, B_SZ, NH_SZ, NP_SZ);

    bf16_t* hin = hxA;
    bf16_t* hout = hxB;
    for (int t = 0; t < T_STEPS; t++) {
        const float* vt = v + (size_t)t * B_SZ * 2;
        // fused gates + cell: grid (NH/32, B/64) = (16,16) = 256 blocks
        gates_cell<<<dim3(NH_SZ / 32, B_SZ / 64), 256, 0, stream>>>(
            hin, whhb, vt, wih, bih, bhh, cxf, hout);
        // g = relu(hx @ g_w^T): 128x128 tiles -> (32,8) = 256 blocks, XCD swizzle
        gemm16<128, 128, 2, true><<<dim3(NG_SZ / 128, B_SZ / 128), 256, 0, stream>>>(
            hout, gwb, nullptr, gbuf + (size_t)(t % C) * B_SZ * NG_SZ, B_SZ, NG_SZ, NH_SZ);
        // chunked batched decoder: 128x128 tiles (800 blocks) + XCD chunk swizzle
        if ((t + 1) % C == 0) {
            int t0 = t + 1 - C;
            gemm16<128, 128, 0, true><<<dim3(NP_SZ / 128, (C * B_SZ) / 128), 256, 0, stream>>>(
                gbuf, decwb, decb, out + (size_t)t0 * B_SZ * NP_SZ, C * B_SZ, NP_SZ, NG_SZ);
        }
        // swap hx buffers
        bf16_t* tmp = hin; hin = hout; hout = tmp;
    }
}